// Round 3
// baseline (1173.862 us; speedup 1.0000x reference)
//
#include <hip/hip_runtime.h>
#include <hip/hip_bf16.h>
#include <math.h>

#define Mrows 4096      // B*T
#define Kdim  256       // F
#define Ncols 16384     // G*V
#define Vsz   8192

typedef __attribute__((ext_vector_type(8))) short bf16x8;
typedef __attribute__((ext_vector_type(4))) float f32x4;

// ---------------- split fp32 -> bf16 (hi, lo) ---------------------------------
__global__ __launch_bounds__(256) void split_bf16(const float* __restrict__ src,
                                                  unsigned short* __restrict__ hi,
                                                  unsigned short* __restrict__ lo) {
    const int i = blockIdx.x * 256 + threadIdx.x;
    const float v = src[i];
    const __hip_bfloat16 h = __float2bfloat16(v);
    const float hf = __bfloat162float(h);
    hi[i] = *(const unsigned short*)&h;
    const __hip_bfloat16 l = __float2bfloat16(v - hf);
    lo[i] = *(const unsigned short*)&l;
}

// ---------------- GEMM: hid[m][n] = sum_k A[m][k]*B[n][k] + bias[n] -----------
// split-bf16 3-term MFMA, 128x128 tile, BK=32, global_load_lds width-16 staging
__global__ __launch_bounds__(256) void gemm_mfma(const unsigned short* __restrict__ Ahi,
                                                 const unsigned short* __restrict__ Alo,
                                                 const unsigned short* __restrict__ Bhi,
                                                 const unsigned short* __restrict__ Blo,
                                                 const float* __restrict__ bias,
                                                 float* __restrict__ hid, int r0) {
    __shared__ unsigned short sAh[128 * 32];
    __shared__ unsigned short sAl[128 * 32];
    __shared__ unsigned short sBh[128 * 32];
    __shared__ unsigned short sBl[128 * 32];
    const int tid = threadIdx.x;
    const int lane = tid & 63;
    const int wave = tid >> 6;
    const int bm = blockIdx.x * 128;            // chunk-local m tile
    const int bn = blockIdx.y * 128;            // n tile
    const int wm = (wave & 1) * 64;
    const int wn = (wave >> 1) * 64;
    const int lm = lane & 15;
    const int kq = (lane >> 4) * 8;

    // staging geometry: per array, wave w stages rows [w*32, w*32+32) as 2 txns
    // of 16 rows; lane -> row = base + lane/4, k-chunk = (lane&3)*8 shorts (16B)
    const int r_in = lane >> 2;                 // 0..15
    const int k8 = (lane & 3) * 8;              // shorts

    f32x4 acc[4][4];
#pragma unroll
    for (int i = 0; i < 4; ++i)
#pragma unroll
        for (int j = 0; j < 4; ++j) acc[i][j] = (f32x4){0.f, 0.f, 0.f, 0.f};

    for (int k0 = 0; k0 < Kdim; k0 += 32) {
        __syncthreads();   // previous compute done before overwrite
#pragma unroll
        for (int t = 0; t < 2; ++t) {
            const int rbase = wave * 32 + t * 16;       // wave-uniform
            const int row = rbase + r_in;
            const size_t ga = (size_t)(r0 + bm + row) * Kdim + k0 + k8;
            const size_t gb = (size_t)(bn + row) * Kdim + k0 + k8;
            const int lds_off = rbase * 32;             // shorts, wave-uniform
            __builtin_amdgcn_global_load_lds(
                (const __attribute__((address_space(1))) void*)(Ahi + ga),
                (__attribute__((address_space(3))) void*)(sAh + lds_off), 16, 0, 0);
            __builtin_amdgcn_global_load_lds(
                (const __attribute__((address_space(1))) void*)(Alo + ga),
                (__attribute__((address_space(3))) void*)(sAl + lds_off), 16, 0, 0);
            __builtin_amdgcn_global_load_lds(
                (const __attribute__((address_space(1))) void*)(Bhi + gb),
                (__attribute__((address_space(3))) void*)(sBh + lds_off), 16, 0, 0);
            __builtin_amdgcn_global_load_lds(
                (const __attribute__((address_space(1))) void*)(Blo + gb),
                (__attribute__((address_space(3))) void*)(sBl + lds_off), 16, 0, 0);
        }
        __syncthreads();   // barrier drains vmcnt (global_load_lds complete)

        bf16x8 ah[4], al[4], bh[4], bl[4];
#pragma unroll
        for (int i = 0; i < 4; ++i) {
            ah[i] = *(const bf16x8*)&sAh[(wm + i * 16 + lm) * 32 + kq];
            al[i] = *(const bf16x8*)&sAl[(wm + i * 16 + lm) * 32 + kq];
            bh[i] = *(const bf16x8*)&sBh[(wn + i * 16 + lm) * 32 + kq];
            bl[i] = *(const bf16x8*)&sBl[(wn + i * 16 + lm) * 32 + kq];
        }
#pragma unroll
        for (int i = 0; i < 4; ++i)
#pragma unroll
            for (int j = 0; j < 4; ++j) {
                acc[i][j] = __builtin_amdgcn_mfma_f32_16x16x32_bf16(ah[i], bh[j], acc[i][j], 0, 0, 0);
                acc[i][j] = __builtin_amdgcn_mfma_f32_16x16x32_bf16(ah[i], bl[j], acc[i][j], 0, 0, 0);
                acc[i][j] = __builtin_amdgcn_mfma_f32_16x16x32_bf16(al[i], bh[j], acc[i][j], 0, 0, 0);
            }
    }

    // epilogue: C/D layout col=lane&15, row=(lane>>4)*4+reg  [m89/m91 verified]
    const int rbase2 = (lane >> 4) * 4;
#pragma unroll
    for (int j = 0; j < 4; ++j) {
        const int n = bn + wn + j * 16 + lm;
        const float bj = bias[n];
#pragma unroll
        for (int i = 0; i < 4; ++i) {
            const int m0 = bm + wm + i * 16 + rbase2;
#pragma unroll
            for (int r2 = 0; r2 < 4; ++r2)
                hid[(size_t)(m0 + r2) * Ncols + n] = acc[i][j][r2] + bj;
        }
    }
}

// ---------------- Phase 2: softmax x2, argmax, codevectors, marginal ----------
// 512 threads, 16 contiguous elements/thread, 8 rows/block
__global__ __launch_bounds__(512, 4) void phase2(const float* __restrict__ hid,
                                                 const float* __restrict__ u,
                                                 const float* __restrict__ emb,
                                                 const int* __restrict__ mask,
                                                 float* __restrict__ marginal,
                                                 float* __restrict__ out,
                                                 int r0) {
    const int g = blockIdx.y;
    const int n0 = r0 + blockIdx.x * 8;
    const int tid = threadIdx.x;
    const int lane = tid & 63;
    const int wid = tid >> 6;                 // 0..7

    __shared__ float marg_s[16 * 512];        // 32 KB, [j][tid] private columns
    __shared__ float sv1[8]; __shared__ int si1[8]; __shared__ float sv2[8];
    __shared__ float ss1[8], ss2[8], scv[8][8];
    __shared__ float sM1, sM2, sS2; __shared__ int sAM;

#pragma unroll
    for (int j = 0; j < 16; ++j) marg_s[(j << 9) + tid] = 0.f;

    const int vbase = tid * 16;
    const float* embg = emb + (size_t)g * Vsz * 8;
    float h[16], lg[16];

    for (int r = 0; r < 8; ++r) {
        const int n = n0 + r;
        const float* hrow = hid + (size_t)(n - r0) * Ncols + (size_t)g * Vsz + vbase;
        const float* urow = u + ((size_t)n * 2 + g) * Vsz + vbase;

        // issue all 8 float4 loads up-front
        float4 uv0 = *(const float4*)(urow + 0);
        float4 uv1 = *(const float4*)(urow + 4);
        float4 uv2 = *(const float4*)(urow + 8);
        float4 uv3 = *(const float4*)(urow + 12);
        float4 hv0 = *(const float4*)(hrow + 0);
        float4 hv1 = *(const float4*)(hrow + 4);
        float4 hv2 = *(const float4*)(hrow + 8);
        float4 hv3 = *(const float4*)(hrow + 12);
        lg[0] = uv0.x; lg[1] = uv0.y; lg[2] = uv0.z; lg[3] = uv0.w;
        lg[4] = uv1.x; lg[5] = uv1.y; lg[6] = uv1.z; lg[7] = uv1.w;
        lg[8] = uv2.x; lg[9] = uv2.y; lg[10] = uv2.z; lg[11] = uv2.w;
        lg[12] = uv3.x; lg[13] = uv3.y; lg[14] = uv3.z; lg[15] = uv3.w;
        h[0] = hv0.x; h[1] = hv0.y; h[2] = hv0.z; h[3] = hv0.w;
        h[4] = hv1.x; h[5] = hv1.y; h[6] = hv1.z; h[7] = hv1.w;
        h[8] = hv2.x; h[9] = hv2.y; h[10] = hv2.z; h[11] = hv2.w;
        h[12] = hv3.x; h[13] = hv3.y; h[14] = hv3.z; h[15] = hv3.w;

        // pass A: gumbel logits + running maxes (first-max-wins = lowest index)
        float mx1 = -INFINITY, mx2 = -INFINITY;
        int am = 0;
#pragma unroll
        for (int j = 0; j < 16; ++j) {
            float uu = fminf(fmaxf(lg[j], 1.17549435e-38f), 1.0f);
            const float d = uu - 1.0f;
            // -log(u): log1p Taylor for u>0.8 (hw-log abs-error zone), else native
            float q = 1.0f / 9.0f;
            q = fmaf(q, d, -0.125f);
            q = fmaf(q, d, 1.0f / 7.0f);
            q = fmaf(q, d, -1.0f / 6.0f);
            q = fmaf(q, d, 0.2f);
            q = fmaf(q, d, -0.25f);
            q = fmaf(q, d, 1.0f / 3.0f);
            q = fmaf(q, d, -0.5f);
            q = fmaf(q, d, 1.0f);
            const float inner = (d > -0.2f) ? (-d) * q : -__logf(uu);
            const float l = h[j] - __logf(inner);
            lg[j] = l;
            if (l > mx1) { mx1 = l; am = vbase + j; }
            mx2 = fmaxf(mx2, h[j]);
        }
        float v1 = mx1; int i1 = am; float v2 = mx2;
#pragma unroll
        for (int off = 32; off > 0; off >>= 1) {
            const float ov = __shfl_down(v1, off);
            const int oi = __shfl_down(i1, off);
            if (ov > v1 || (ov == v1 && oi < i1)) { v1 = ov; i1 = oi; }
            v2 = fmaxf(v2, __shfl_down(v2, off));
        }
        if (lane == 0) { sv1[wid] = v1; si1[wid] = i1; sv2[wid] = v2; }
        __syncthreads();
        if (tid == 0) {
            float bv = sv1[0]; int bi = si1[0]; float b2 = sv2[0];
            for (int w2 = 1; w2 < 8; ++w2) {
                if (sv1[w2] > bv || (sv1[w2] == bv && si1[w2] < bi)) { bv = sv1[w2]; bi = si1[w2]; }
                b2 = fmaxf(b2, sv2[w2]);
            }
            sM1 = bv; sAM = bi; sM2 = b2;
        }
        __syncthreads();
        const float M1 = sM1;
        const float M2 = sM2;

        // pass B: sums + codevectors; h[] becomes clean exp terms
        float s1 = 0.f, s2 = 0.f;
        float cv[8];
#pragma unroll
        for (int d2 = 0; d2 < 8; ++d2) cv[d2] = 0.f;
#pragma unroll
        for (int j = 0; j < 16; ++j) {
            const float p = __expf(lg[j] - M1);
            s1 += p;
            const float* e = embg + (size_t)(vbase + j) * 8;
            const float4 e0 = *(const float4*)(e);
            const float4 e1 = *(const float4*)(e + 4);
            cv[0] = fmaf(p, e0.x, cv[0]); cv[1] = fmaf(p, e0.y, cv[1]);
            cv[2] = fmaf(p, e0.z, cv[2]); cv[3] = fmaf(p, e0.w, cv[3]);
            cv[4] = fmaf(p, e1.x, cv[4]); cv[5] = fmaf(p, e1.y, cv[5]);
            cv[6] = fmaf(p, e1.z, cv[6]); cv[7] = fmaf(p, e1.w, cv[7]);
            const float qv = __expf(h[j] - M2);
            s2 += qv;
            h[j] = qv;
        }
#pragma unroll
        for (int off = 32; off > 0; off >>= 1) {
            s1 += __shfl_down(s1, off);
            s2 += __shfl_down(s2, off);
        }
#pragma unroll
        for (int d2 = 0; d2 < 8; ++d2)
#pragma unroll
            for (int off = 32; off > 0; off >>= 1) cv[d2] += __shfl_down(cv[d2], off);
        if (lane == 0) {
            ss1[wid] = s1; ss2[wid] = s2;
#pragma unroll
            for (int d2 = 0; d2 < 8; ++d2) scv[wid][d2] = cv[d2];
        }
        __syncthreads();
        if (tid < 8) {
            float c = 0.f, S1 = 0.f;
            for (int w2 = 0; w2 < 8; ++w2) { c += scv[w2][tid]; S1 += ss1[w2]; }
            out[(size_t)n * 16 + g * 8 + tid] = c / S1;
        }
        if (tid == 8) {
            float S2 = 0.f;
            for (int w2 = 0; w2 < 8; ++w2) S2 += ss2[w2];
            sS2 = S2;
        }
        if (tid == 9) out[65537 + (size_t)n * 2 + g] = (float)sAM;
        __syncthreads();
        if (mask[n] != 0) {
            const float invS2 = 1.0f / sS2;
#pragma unroll
            for (int j = 0; j < 16; ++j)
                marg_s[(j << 9) + tid] = fmaf(h[j], invS2, marg_s[(j << 9) + tid]);
        }
        __syncthreads();
    }
#pragma unroll
    for (int j = 0; j < 16; ++j)
        atomicAdd(&marginal[g * Vsz + vbase + j], marg_s[(j << 9) + tid]);
}

// ---------------- Perplexity --------------------------------------------------
__global__ __launch_bounds__(256) void ppl_kernel(const float* __restrict__ marginal,
                                                  const int* __restrict__ mask,
                                                  float* __restrict__ out) {
    const int tid = threadIdx.x;
    const int lane = tid & 63;
    const int wid = tid >> 6;
    __shared__ float red[4];
    __shared__ int redi[4];

    int ms = 0;
    for (int i = tid; i < Mrows; i += 256) ms += mask[i];
#pragma unroll
    for (int off = 32; off > 0; off >>= 1) ms += __shfl_down(ms, off);
    if (lane == 0) redi[wid] = ms;
    __syncthreads();
    const float inv = 1.0f / (float)(redi[0] + redi[1] + redi[2] + redi[3]);

    float ppl = 0.f;
    for (int g = 0; g < 2; ++g) {
        float part = 0.f;
        for (int v = tid; v < Vsz; v += 256) {
            const float m = marginal[g * Vsz + v] * inv;
            part += m * logf(m + 1e-7f);
        }
#pragma unroll
        for (int off = 32; off > 0; off >>= 1) part += __shfl_down(part, off);
        __syncthreads();
        if (lane == 0) red[wid] = part;
        __syncthreads();
        if (tid == 0) ppl += __expf(-(red[0] + red[1] + red[2] + red[3]));
        __syncthreads();
    }
    if (tid == 0) out[65536] = ppl;
}

// ---------------- Launch ------------------------------------------------------
extern "C" void kernel_launch(void* const* d_in, const int* in_sizes, int n_in,
                              void* d_out, int out_size, void* d_ws, size_t ws_size,
                              hipStream_t stream) {
    const float* x    = (const float*)d_in[0];
    const float* u    = (const float*)d_in[1];
    const float* emb  = (const float*)d_in[2];
    const float* w    = (const float*)d_in[3];
    const float* bias = (const float*)d_in[4];
    const int*   mask = (const int*)d_in[5];
    float* out = (float*)d_out;

    char* base = (char*)d_ws;
    float* marginal = (float*)base;                                    // 64 KB
    unsigned short* Ahi = (unsigned short*)(base + 65536);             // 2 MB
    unsigned short* Alo = Ahi + 1048576;                               // 2 MB
    unsigned short* Bhi = Alo + 1048576;                               // 8 MB
    unsigned short* Blo = Bhi + 4194304;                               // 8 MB
    const size_t hid_off = 65536 + 4194304 + 16777216;                 // ~21 MB
    float* hid = (float*)(base + hid_off);

    size_t cap_rows = (ws_size > hid_off) ? (ws_size - hid_off) / ((size_t)Ncols * 4) : 0;
    int cr = (cap_rows >= Mrows) ? Mrows : (int)((cap_rows / 128) * 128);
    if (cr < 128) cr = 128;

    hipMemsetAsync(marginal, 0, 65536, stream);
    split_bf16<<<4096, 256, 0, stream>>>(x, Ahi, Alo);      // 1M elems
    split_bf16<<<16384, 256, 0, stream>>>(w, Bhi, Blo);     // 4M elems

    for (int r0 = 0; r0 < Mrows; r0 += cr) {
        const int rows = (Mrows - r0 < cr) ? (Mrows - r0) : cr;
        dim3 gg(rows / 128, Ncols / 128);
        gemm_mfma<<<gg, 256, 0, stream>>>(Ahi, Alo, Bhi, Blo, bias, hid, r0);
        dim3 pg(rows / 8, 2);
        phase2<<<pg, 512, 0, stream>>>(hid, u, emb, mask, marginal, out, r0);
    }
    ppl_kernel<<<1, 256, 0, stream>>>(marginal, mask, out);
}

// Round 4
// 1087.963 us; speedup vs baseline: 1.0790x; 1.0790x over previous
//
#include <hip/hip_runtime.h>
#include <hip/hip_bf16.h>
#include <math.h>

#define Mrows 4096      // B*T
#define Kdim  256       // F
#define Ncols 16384     // G*V
#define Vsz   8192

typedef __attribute__((ext_vector_type(8))) short bf16x8;
typedef __attribute__((ext_vector_type(4))) float f32x4;

// ---------------- split fp32 -> bf16 (hi, lo) ---------------------------------
__global__ __launch_bounds__(256) void split_bf16(const float* __restrict__ src,
                                                  unsigned short* __restrict__ hi,
                                                  unsigned short* __restrict__ lo) {
    const int i = blockIdx.x * 256 + threadIdx.x;
    const float v = src[i];
    const __hip_bfloat16 h = __float2bfloat16(v);
    const float hf = __bfloat162float(h);
    hi[i] = *(const unsigned short*)&h;
    const __hip_bfloat16 l = __float2bfloat16(v - hf);
    lo[i] = *(const unsigned short*)&l;
}

// ---------------- GEMM: hid[m][n] = sum_k A[m][k]*B[n][k] + bias[n] -----------
// split-bf16 3-term MFMA, 128x128 tile, BK=32, global_load_lds width-16 staging
__global__ __launch_bounds__(256) void gemm_mfma(const unsigned short* __restrict__ Ahi,
                                                 const unsigned short* __restrict__ Alo,
                                                 const unsigned short* __restrict__ Bhi,
                                                 const unsigned short* __restrict__ Blo,
                                                 const float* __restrict__ bias,
                                                 float* __restrict__ hid, int r0) {
    __shared__ unsigned short sAh[128 * 32];
    __shared__ unsigned short sAl[128 * 32];
    __shared__ unsigned short sBh[128 * 32];
    __shared__ unsigned short sBl[128 * 32];
    const int tid = threadIdx.x;
    const int lane = tid & 63;
    const int wave = tid >> 6;
    const int bm = blockIdx.x * 128;            // chunk-local m tile
    const int bn = blockIdx.y * 128;            // n tile
    const int wm = (wave & 1) * 64;
    const int wn = (wave >> 1) * 64;
    const int lm = lane & 15;
    const int kq = (lane >> 4) * 8;

    // staging geometry: lane -> row = base + lane/4, k-chunk = (lane&3)*8 shorts
    const int r_in = lane >> 2;                 // 0..15
    const int k8 = (lane & 3) * 8;              // shorts

    f32x4 acc[4][4];
#pragma unroll
    for (int i = 0; i < 4; ++i)
#pragma unroll
        for (int j = 0; j < 4; ++j) acc[i][j] = (f32x4){0.f, 0.f, 0.f, 0.f};

    for (int k0 = 0; k0 < Kdim; k0 += 32) {
        __syncthreads();   // previous compute done before overwrite
#pragma unroll
        for (int t = 0; t < 2; ++t) {
            const int rbase = wave * 32 + t * 16;       // wave-uniform
            const int row = rbase + r_in;
            const size_t ga = (size_t)(r0 + bm + row) * Kdim + k0 + k8;
            const size_t gb = (size_t)(bn + row) * Kdim + k0 + k8;
            const int lds_off = rbase * 32;             // shorts, wave-uniform
            __builtin_amdgcn_global_load_lds(
                (const __attribute__((address_space(1))) void*)(Ahi + ga),
                (__attribute__((address_space(3))) void*)(sAh + lds_off), 16, 0, 0);
            __builtin_amdgcn_global_load_lds(
                (const __attribute__((address_space(1))) void*)(Alo + ga),
                (__attribute__((address_space(3))) void*)(sAl + lds_off), 16, 0, 0);
            __builtin_amdgcn_global_load_lds(
                (const __attribute__((address_space(1))) void*)(Bhi + gb),
                (__attribute__((address_space(3))) void*)(sBh + lds_off), 16, 0, 0);
            __builtin_amdgcn_global_load_lds(
                (const __attribute__((address_space(1))) void*)(Blo + gb),
                (__attribute__((address_space(3))) void*)(sBl + lds_off), 16, 0, 0);
        }
        __syncthreads();   // barrier drains vmcnt (global_load_lds complete)

        bf16x8 ah[4], al[4], bh[4], bl[4];
#pragma unroll
        for (int i = 0; i < 4; ++i) {
            ah[i] = *(const bf16x8*)&sAh[(wm + i * 16 + lm) * 32 + kq];
            al[i] = *(const bf16x8*)&sAl[(wm + i * 16 + lm) * 32 + kq];
            bh[i] = *(const bf16x8*)&sBh[(wn + i * 16 + lm) * 32 + kq];
            bl[i] = *(const bf16x8*)&sBl[(wn + i * 16 + lm) * 32 + kq];
        }
#pragma unroll
        for (int i = 0; i < 4; ++i)
#pragma unroll
            for (int j = 0; j < 4; ++j) {
                acc[i][j] = __builtin_amdgcn_mfma_f32_16x16x32_bf16(ah[i], bh[j], acc[i][j], 0, 0, 0);
                acc[i][j] = __builtin_amdgcn_mfma_f32_16x16x32_bf16(ah[i], bl[j], acc[i][j], 0, 0, 0);
                acc[i][j] = __builtin_amdgcn_mfma_f32_16x16x32_bf16(al[i], bh[j], acc[i][j], 0, 0, 0);
            }
    }

    // epilogue: C/D layout col=lane&15, row=(lane>>4)*4+reg  [m89/m91 verified]
    const int rbase2 = (lane >> 4) * 4;
#pragma unroll
    for (int j = 0; j < 4; ++j) {
        const int n = bn + wn + j * 16 + lm;
        const float bj = bias[n];
#pragma unroll
        for (int i = 0; i < 4; ++i) {
            const int m0 = bm + wm + i * 16 + rbase2;
#pragma unroll
            for (int r2 = 0; r2 < 4; ++r2)
                hid[(size_t)(m0 + r2) * Ncols + n] = acc[i][j][r2] + bj;
        }
    }
}

// ---------------- Phase 2: softmax x2, argmax, codevectors, marginal ----------
// 512 threads, 16 contiguous elements/thread, 8 rows/block
// __launch_bounds__(512,2): R3's (512,4) capped VGPR at 64 -> scratch spills
// (+947 MB HBM traffic, 815 us). Min-waves=2 lets allocator keep ~100 live regs.
__global__ __launch_bounds__(512, 2) void phase2(const float* __restrict__ hid,
                                                 const float* __restrict__ u,
                                                 const float* __restrict__ emb,
                                                 const int* __restrict__ mask,
                                                 float* __restrict__ marginal,
                                                 float* __restrict__ out,
                                                 int r0) {
    const int g = blockIdx.y;
    const int n0 = r0 + blockIdx.x * 8;
    const int tid = threadIdx.x;
    const int lane = tid & 63;
    const int wid = tid >> 6;                 // 0..7

    __shared__ float marg_s[16 * 512];        // 32 KB, [j][tid] private columns
    __shared__ float sv1[8]; __shared__ int si1[8]; __shared__ float sv2[8];
    __shared__ float ss1[8], ss2[8], scv[8][8];
    __shared__ float sM1, sM2, sS2; __shared__ int sAM;

#pragma unroll
    for (int j = 0; j < 16; ++j) marg_s[(j << 9) + tid] = 0.f;

    const int vbase = tid * 16;
    const float* embg = emb + (size_t)g * Vsz * 8;
    float h[16], lg[16];

    for (int r = 0; r < 8; ++r) {
        const int n = n0 + r;
        const float* hrow = hid + (size_t)(n - r0) * Ncols + (size_t)g * Vsz + vbase;
        const float* urow = u + ((size_t)n * 2 + g) * Vsz + vbase;

        // issue all 8 float4 loads up-front
        float4 uv0 = *(const float4*)(urow + 0);
        float4 uv1 = *(const float4*)(urow + 4);
        float4 uv2 = *(const float4*)(urow + 8);
        float4 uv3 = *(const float4*)(urow + 12);
        float4 hv0 = *(const float4*)(hrow + 0);
        float4 hv1 = *(const float4*)(hrow + 4);
        float4 hv2 = *(const float4*)(hrow + 8);
        float4 hv3 = *(const float4*)(hrow + 12);
        lg[0] = uv0.x; lg[1] = uv0.y; lg[2] = uv0.z; lg[3] = uv0.w;
        lg[4] = uv1.x; lg[5] = uv1.y; lg[6] = uv1.z; lg[7] = uv1.w;
        lg[8] = uv2.x; lg[9] = uv2.y; lg[10] = uv2.z; lg[11] = uv2.w;
        lg[12] = uv3.x; lg[13] = uv3.y; lg[14] = uv3.z; lg[15] = uv3.w;
        h[0] = hv0.x; h[1] = hv0.y; h[2] = hv0.z; h[3] = hv0.w;
        h[4] = hv1.x; h[5] = hv1.y; h[6] = hv1.z; h[7] = hv1.w;
        h[8] = hv2.x; h[9] = hv2.y; h[10] = hv2.z; h[11] = hv2.w;
        h[12] = hv3.x; h[13] = hv3.y; h[14] = hv3.z; h[15] = hv3.w;

        // pass A: gumbel logits + running maxes (first-max-wins = lowest index)
        float mx1 = -INFINITY, mx2 = -INFINITY;
        int am = 0;
#pragma unroll
        for (int j = 0; j < 16; ++j) {
            float uu = fminf(fmaxf(lg[j], 1.17549435e-38f), 1.0f);
            const float d = uu - 1.0f;
            // -log(u): log1p Taylor for u>0.8 (hw-log abs-error zone), else native
            float q = 1.0f / 9.0f;
            q = fmaf(q, d, -0.125f);
            q = fmaf(q, d, 1.0f / 7.0f);
            q = fmaf(q, d, -1.0f / 6.0f);
            q = fmaf(q, d, 0.2f);
            q = fmaf(q, d, -0.25f);
            q = fmaf(q, d, 1.0f / 3.0f);
            q = fmaf(q, d, -0.5f);
            q = fmaf(q, d, 1.0f);
            const float inner = (d > -0.2f) ? (-d) * q : -__logf(uu);
            const float l = h[j] - __logf(inner);
            lg[j] = l;
            if (l > mx1) { mx1 = l; am = vbase + j; }
            mx2 = fmaxf(mx2, h[j]);
        }
        float v1 = mx1; int i1 = am; float v2 = mx2;
#pragma unroll
        for (int off = 32; off > 0; off >>= 1) {
            const float ov = __shfl_down(v1, off);
            const int oi = __shfl_down(i1, off);
            if (ov > v1 || (ov == v1 && oi < i1)) { v1 = ov; i1 = oi; }
            v2 = fmaxf(v2, __shfl_down(v2, off));
        }
        if (lane == 0) { sv1[wid] = v1; si1[wid] = i1; sv2[wid] = v2; }
        __syncthreads();
        if (tid == 0) {
            float bv = sv1[0]; int bi = si1[0]; float b2 = sv2[0];
            for (int w2 = 1; w2 < 8; ++w2) {
                if (sv1[w2] > bv || (sv1[w2] == bv && si1[w2] < bi)) { bv = sv1[w2]; bi = si1[w2]; }
                b2 = fmaxf(b2, sv2[w2]);
            }
            sM1 = bv; sAM = bi; sM2 = b2;
        }
        __syncthreads();
        const float M1 = sM1;
        const float M2 = sM2;

        // pass B: sums + codevectors; h[] becomes clean exp terms
        float s1 = 0.f, s2 = 0.f;
        float cv[8];
#pragma unroll
        for (int d2 = 0; d2 < 8; ++d2) cv[d2] = 0.f;
#pragma unroll
        for (int j = 0; j < 16; ++j) {
            const float p = __expf(lg[j] - M1);
            s1 += p;
            const float* e = embg + (size_t)(vbase + j) * 8;
            const float4 e0 = *(const float4*)(e);
            const float4 e1 = *(const float4*)(e + 4);
            cv[0] = fmaf(p, e0.x, cv[0]); cv[1] = fmaf(p, e0.y, cv[1]);
            cv[2] = fmaf(p, e0.z, cv[2]); cv[3] = fmaf(p, e0.w, cv[3]);
            cv[4] = fmaf(p, e1.x, cv[4]); cv[5] = fmaf(p, e1.y, cv[5]);
            cv[6] = fmaf(p, e1.z, cv[6]); cv[7] = fmaf(p, e1.w, cv[7]);
            const float qv = __expf(h[j] - M2);
            s2 += qv;
            h[j] = qv;
        }
#pragma unroll
        for (int off = 32; off > 0; off >>= 1) {
            s1 += __shfl_down(s1, off);
            s2 += __shfl_down(s2, off);
        }
#pragma unroll
        for (int d2 = 0; d2 < 8; ++d2)
#pragma unroll
            for (int off = 32; off > 0; off >>= 1) cv[d2] += __shfl_down(cv[d2], off);
        if (lane == 0) {
            ss1[wid] = s1; ss2[wid] = s2;
#pragma unroll
            for (int d2 = 0; d2 < 8; ++d2) scv[wid][d2] = cv[d2];
        }
        __syncthreads();
        if (tid < 8) {
            float c = 0.f, S1 = 0.f;
            for (int w2 = 0; w2 < 8; ++w2) { c += scv[w2][tid]; S1 += ss1[w2]; }
            out[(size_t)n * 16 + g * 8 + tid] = c / S1;
        }
        if (tid == 8) {
            float S2 = 0.f;
            for (int w2 = 0; w2 < 8; ++w2) S2 += ss2[w2];
            sS2 = S2;
        }
        if (tid == 9) out[65537 + (size_t)n * 2 + g] = (float)sAM;
        __syncthreads();
        if (mask[n] != 0) {
            const float invS2 = 1.0f / sS2;
#pragma unroll
            for (int j = 0; j < 16; ++j)
                marg_s[(j << 9) + tid] = fmaf(h[j], invS2, marg_s[(j << 9) + tid]);
        }
        __syncthreads();
    }
#pragma unroll
    for (int j = 0; j < 16; ++j)
        atomicAdd(&marginal[g * Vsz + vbase + j], marg_s[(j << 9) + tid]);
}

// ---------------- Perplexity --------------------------------------------------
__global__ __launch_bounds__(256) void ppl_kernel(const float* __restrict__ marginal,
                                                  const int* __restrict__ mask,
                                                  float* __restrict__ out) {
    const int tid = threadIdx.x;
    const int lane = tid & 63;
    const int wid = tid >> 6;
    __shared__ float red[4];
    __shared__ int redi[4];

    int ms = 0;
    for (int i = tid; i < Mrows; i += 256) ms += mask[i];
#pragma unroll
    for (int off = 32; off > 0; off >>= 1) ms += __shfl_down(ms, off);
    if (lane == 0) redi[wid] = ms;
    __syncthreads();
    const float inv = 1.0f / (float)(redi[0] + redi[1] + redi[2] + redi[3]);

    float ppl = 0.f;
    for (int g = 0; g < 2; ++g) {
        float part = 0.f;
        for (int v = tid; v < Vsz; v += 256) {
            const float m = marginal[g * Vsz + v] * inv;
            part += m * logf(m + 1e-7f);
        }
#pragma unroll
        for (int off = 32; off > 0; off >>= 1) part += __shfl_down(part, off);
        __syncthreads();
        if (lane == 0) red[wid] = part;
        __syncthreads();
        if (tid == 0) ppl += __expf(-(red[0] + red[1] + red[2] + red[3]));
        __syncthreads();
    }
    if (tid == 0) out[65536] = ppl;
}

// ---------------- Launch ------------------------------------------------------
extern "C" void kernel_launch(void* const* d_in, const int* in_sizes, int n_in,
                              void* d_out, int out_size, void* d_ws, size_t ws_size,
                              hipStream_t stream) {
    const float* x    = (const float*)d_in[0];
    const float* u    = (const float*)d_in[1];
    const float* emb  = (const float*)d_in[2];
    const float* w    = (const float*)d_in[3];
    const float* bias = (const float*)d_in[4];
    const int*   mask = (const int*)d_in[5];
    float* out = (float*)d_out;

    char* base = (char*)d_ws;
    float* marginal = (float*)base;                                    // 64 KB
    unsigned short* Ahi = (unsigned short*)(base + 65536);             // 2 MB
    unsigned short* Alo = Ahi + 1048576;                               // 2 MB
    unsigned short* Bhi = Alo + 1048576;                               // 8 MB
    unsigned short* Blo = Bhi + 4194304;                               // 8 MB
    const size_t hid_off = 65536 + 4194304 + 16777216;                 // ~21 MB
    float* hid = (float*)(base + hid_off);

    size_t cap_rows = (ws_size > hid_off) ? (ws_size - hid_off) / ((size_t)Ncols * 4) : 0;
    int cr = (cap_rows >= Mrows) ? Mrows : (int)((cap_rows / 128) * 128);
    if (cr < 128) cr = 128;

    hipMemsetAsync(marginal, 0, 65536, stream);
    split_bf16<<<4096, 256, 0, stream>>>(x, Ahi, Alo);      // 1M elems
    split_bf16<<<16384, 256, 0, stream>>>(w, Bhi, Blo);     // 4M elems

    for (int r0 = 0; r0 < Mrows; r0 += cr) {
        const int rows = (Mrows - r0 < cr) ? (Mrows - r0) : cr;
        dim3 gg(rows / 128, Ncols / 128);
        gemm_mfma<<<gg, 256, 0, stream>>>(Ahi, Alo, Bhi, Blo, bias, hid, r0);
        dim3 pg(rows / 8, 2);
        phase2<<<pg, 512, 0, stream>>>(hid, u, emb, mask, marginal, out, r0);
    }
    ppl_kernel<<<1, 256, 0, stream>>>(marginal, mask, out);
}